// Round 8
// baseline (91.914 us; speedup 1.0000x reference)
//
#include <hip/hip_runtime.h>
#include <math.h>

// Problem constants (fixed by the reference setup)
constexpr int BB = 64, LL = 512, DD = 768, SS = 30;
constexpr int NDOMc = 5, NGATEc = 3, PRED = 2;

// Output layout (flat float32, reference return order)
constexpr size_t O_DOM   = 0;                               // (B,5)
constexpr size_t O_SPP   = O_DOM   + (size_t)BB*NDOMc;      // (B,30) sigmoid
constexpr size_t O_GATE  = O_SPP   + (size_t)BB*SS;         // (B,30,3) softmax
constexpr size_t O_SPTR  = O_GATE  + (size_t)BB*SS*NGATEc;  // (B,30) passthrough
constexpr size_t O_SGATE = O_SPTR  + (size_t)BB*SS;         // (B,30) passthrough
constexpr size_t O_SPROB = O_SGATE + (size_t)BB*SS;         // (B,30,512)
constexpr size_t O_EPROB = O_SPROB + (size_t)BB*SS*LL;      // (B,30,512)

// Workspace layout (floats): WgW[30*768*3], bgW[96], then ints
constexpr int WS_WGW = 0;
constexpr int WS_BGW = SS*DD*NGATEc;        // 69120
constexpr int WS_INT = WS_BGW + 96;         // 69216 (float offset where ints start)

constexpr int KB_ROWS = SS*DD + SS;         // 23070
constexpr int MAXW = BB * 4;                              // 256 items max (4-slot items)
constexpr int NCH = 32;                                   // 32 chunks x 16 rows
constexpr int KD_BLOCKS = MAXW * NCH;                     // 8192
constexpr int KB_BLOCKS = (KB_ROWS/2 + 3) / 4;            // 2884

__device__ __forceinline__ float wred64(float v) {
    #pragma unroll
    for (int o = 32; o; o >>= 1) v += __shfl_xor(v, o);
    return v;
}

// ---------- Kernel A: per-batch small dots, passthrough, scan/compaction ----
__global__ __launch_bounds__(256) void kA(
    const float* __restrict__ cls, const float* __restrict__ Wdom,
    const float* __restrict__ bdom, const float* __restrict__ Wslot,
    const float* __restrict__ bslot, const int* __restrict__ sp,
    const int* __restrict__ sg, float* __restrict__ out,
    int* __restrict__ nptr, int* __restrict__ nsel,
    int* __restrict__ ptrpos, int* __restrict__ selpos)
{
    const int b = blockIdx.x;
    const int tid = threadIdx.x, lane = tid & 63, wid = tid >> 6;
    const float* c = cls + (size_t)b * DD;

    for (int t = wid; t < NDOMc + SS; t += 4) {
        float acc = 0.f;
        if (t < NDOMc) {
            for (int d = lane; d < DD; d += 64) acc += c[d] * Wdom[d*NDOMc + t];
        } else {
            const int j = t - NDOMc;
            for (int d = lane; d < DD; d += 64) acc += c[d] * Wslot[d*SS + j];
        }
        acc = wred64(acc);
        if (lane == 0) {
            if (t < NDOMc) out[O_DOM + (size_t)b*NDOMc + t] = acc + bdom[t];
            else {
                const int j = t - NDOMc;
                const float x = acc + bslot[j];
                out[O_SPP + (size_t)b*SS + j] = 1.f / (1.f + expf(-x));
            }
        }
    }
    if (tid < SS) {
        out[O_SPTR  + (size_t)b*SS + tid] = (float)sp[b*SS + tid];
        out[O_SGATE + (size_t)b*SS + tid] = (float)sg[b*SS + tid];
    }
    // serial scan: ptr ranks and pmask compaction.
    // NOTE: gate_at_slot = slot_gate[b, clip(csum-1,0,M-1)] -> indexed by RANK.
    if (tid == 0) {
        int cp = 0, cs = 0;
        for (int i = 0; i < SS; ++i) {
            if (sp[b*SS + i] == 1) {
                const int rank = cp;            // csum-1 at this position
                ptrpos[b*SS + rank] = i;
                ++cp;
                if (sg[b*SS + rank] == PRED) { selpos[b*SS + cs] = i; ++cs; }
            }
        }
        nptr[b] = cp; nsel[b] = cs;
    }
}

// ---------- Kernel A2: compact (b, 4-slot group) work items, sorted by b ----
__global__ __launch_bounds__(64) void kA2(
    const int* __restrict__ nsel, int* __restrict__ items, int* __restrict__ NW)
{
    const int lane = threadIdx.x;               // 1 wave, lane == b
    const int ns = nsel[lane];
    const int cnt = (ns + 3) >> 2;              // ceil(ns/4) items
    int off = cnt;
    #pragma unroll
    for (int d = 1; d < 64; d <<= 1) {          // inclusive scan
        const int t = __shfl_up(off, d);
        if (lane >= d) off += t;
    }
    off -= cnt;                                 // exclusive prefix
    for (int i = 0; i < cnt; ++i) items[off + i] = lane * SS + 4*i;
    if (lane == 63) *NW = off + cnt;
}

// ---------- fused kBD: kB blocks first, then w-major/c-minor score blocks ---
__global__ __launch_bounds__(256) void kBD(
    const float* __restrict__ H, const float* __restrict__ Ws,
    const float* __restrict__ We, const int* __restrict__ nsel,
    const int* __restrict__ selpos, float* __restrict__ out,
    const float* __restrict__ Wg, const float* __restrict__ bg,
    const float* __restrict__ Wgate,
    float* __restrict__ WgW, float* __restrict__ bgW,
    const int* __restrict__ items, const int* __restrict__ NW)
{
    const int bid = blockIdx.x;
    const int tid = threadIdx.x;

    if (bid >= KB_BLOCKS) {
        // ---- scores: w-major / c-minor. Chunk c -> fixed XCD (32%8==0), so
        // same-(b,c) re-reads across a batch's items stay in one L2.
        // Dead blocks (w >= NW) form ONE contiguous tail of the grid.
        const int bidd = bid - KB_BLOCKS;
        const int w = bidd >> 5;                    // item index (major)
        const int c = bidd & 31;                    // chunk (minor)
        if (w >= *NW) return;
        const int item = items[w];
        const int b = item / SS, k0 = item % SS;
        const int ns = nsel[b];

        const int grp = tid >> 4, m = tid & 15;     // 16 groups x 16 lanes
        const int l = c * 16 + grp;                 // this group's row

        // H row slice in registers (48 floats/lane), read from HBM/L2 once
        const float4* h4 = (const float4*)(H + ((size_t)b * LL + l) * DD);
        float4 hr[12];
        #pragma unroll
        for (int j = 0; j < 12; ++j) hr[j] = h4[j*16 + m];

        #pragma unroll 2
        for (int p = 0; p < 2; ++p) {
            const int ka = k0 + 2*p;
            if (ka < ns) {
                const bool two = (ka + 1 < ns);
                const int s0 = selpos[b*SS + ka];
                const int s1 = two ? selpos[b*SS + ka + 1] : s0;
                const float4* wsa = (const float4*)(Ws + (size_t)s0 * DD);
                const float4* wea = (const float4*)(We + (size_t)s0 * DD);
                const float4* wsb = (const float4*)(Ws + (size_t)s1 * DD);
                const float4* web = (const float4*)(We + (size_t)s1 * DD);

                float as0=0.f, ae0=0.f, as1=0.f, ae1=0.f;
                #pragma unroll
                for (int j = 0; j < 12; ++j) {
                    const float4 w0 = wsa[j*16 + m];
                    const float4 u0 = wea[j*16 + m];
                    const float4 w1 = wsb[j*16 + m];
                    const float4 u1 = web[j*16 + m];
                    as0 += hr[j].x*w0.x + hr[j].y*w0.y + hr[j].z*w0.z + hr[j].w*w0.w;
                    ae0 += hr[j].x*u0.x + hr[j].y*u0.y + hr[j].z*u0.z + hr[j].w*u0.w;
                    as1 += hr[j].x*w1.x + hr[j].y*w1.y + hr[j].z*w1.z + hr[j].w*w1.w;
                    ae1 += hr[j].x*u1.x + hr[j].y*u1.y + hr[j].z*u1.z + hr[j].w*u1.w;
                }
                #pragma unroll
                for (int o = 8; o; o >>= 1) {
                    as0 += __shfl_xor(as0, o); ae0 += __shfl_xor(ae0, o);
                    as1 += __shfl_xor(as1, o); ae1 += __shfl_xor(ae1, o);
                }
                if (m == 0) {
                    out[O_SPROB + (size_t)(b*SS + ka) * LL + l] = as0;
                    out[O_EPROB + (size_t)(b*SS + ka) * LL + l] = ae0;
                    if (two) {
                        out[O_SPROB + (size_t)(b*SS + ka + 1) * LL + l] = as1;
                        out[O_EPROB + (size_t)(b*SS + ka + 1) * LL + l] = ae1;
                    }
                }
            }
        }
        return;
    }

    // ---- WgW precompute (bid < KB_BLOCKS): 2 rows per wave; pure HBM stream -
    const int lane = tid & 63, wid = tid >> 6;
    const int r0 = (bid * 4 + wid) * 2;
    if (r0 >= KB_ROWS) return;

    float wgt[3][4][3];
    #pragma unroll
    for (int j = 0; j < 3; ++j)
        #pragma unroll
        for (int cc = 0; cc < 4; ++cc) {
            const int e = j*256 + lane*4 + cc;
            #pragma unroll
            for (int g = 0; g < NGATEc; ++g) wgt[j][cc][g] = Wgate[e*NGATEc + g];
        }

    const float* src0 = (r0 < SS*DD) ? Wg + (size_t)r0*DD : bg + (size_t)(r0 - SS*DD)*DD;
    const int r1 = r0 + 1;
    const float* src1 = (r1 < SS*DD) ? Wg + (size_t)r1*DD : bg + (size_t)(r1 - SS*DD)*DD;
    float* dst0 = (r0 < SS*DD) ? WgW + (size_t)r0*3 : bgW + (r0 - SS*DD)*3;
    float* dst1 = (r1 < SS*DD) ? WgW + (size_t)r1*3 : bgW + (r1 - SS*DD)*3;

    const float4* s40 = (const float4*)src0;
    const float4* s41 = (const float4*)src1;
    float a0=0,a1=0,a2=0, c0=0,c1=0,c2=0;
    #pragma unroll
    for (int j = 0; j < 3; ++j) {
        const float4 v = s40[j*64 + lane];
        const float4 w2 = s41[j*64 + lane];
        a0 += v.x*wgt[j][0][0] + v.y*wgt[j][1][0] + v.z*wgt[j][2][0] + v.w*wgt[j][3][0];
        a1 += v.x*wgt[j][0][1] + v.y*wgt[j][1][1] + v.z*wgt[j][2][1] + v.w*wgt[j][3][1];
        a2 += v.x*wgt[j][0][2] + v.y*wgt[j][1][2] + v.z*wgt[j][2][2] + v.w*wgt[j][3][2];
        c0 += w2.x*wgt[j][0][0] + w2.y*wgt[j][1][0] + w2.z*wgt[j][2][0] + w2.w*wgt[j][3][0];
        c1 += w2.x*wgt[j][0][1] + w2.y*wgt[j][1][1] + w2.z*wgt[j][2][1] + w2.w*wgt[j][3][1];
        c2 += w2.x*wgt[j][0][2] + w2.y*wgt[j][1][2] + w2.z*wgt[j][2][2] + w2.w*wgt[j][3][2];
    }
    a0 = wred64(a0); a1 = wred64(a1); a2 = wred64(a2);
    c0 = wred64(c0); c1 = wred64(c1); c2 = wred64(c2);
    if (lane == 0) {
        dst0[0] = a0; dst0[1] = a1; dst0[2] = a2;
        dst1[0] = c0; dst1[1] = c1; dst1[2] = c2;
    }
}

// ---------- Kernel C: slot_gate_prob ----------------------------------------
__global__ __launch_bounds__(256) void kC(
    const float* __restrict__ cls, const float* __restrict__ WgW,
    const float* __restrict__ bgW, const float* __restrict__ bgate,
    const int* __restrict__ nptr, const int* __restrict__ ptrpos,
    float* __restrict__ out)
{
    const int lane = threadIdx.x & 63, wid = threadIdx.x >> 6;
    const int idx = blockIdx.x * 4 + wid;       // b*SS + m
    if (idx >= BB*SS) return;
    const int b = idx / SS, m = idx % SS;

    float s0, s1, s2;
    if (m < nptr[b]) {
        const int s = ptrpos[b*SS + m];
        const float4* c4 = (const float4*)(cls + (size_t)b * DD);
        float a0 = 0.f, a1 = 0.f, a2 = 0.f;
        #pragma unroll
        for (int j = 0; j < 3; ++j) {
            const float4 v = c4[j*64 + lane];
            const float* wp = WgW + ((size_t)s*DD + j*256 + lane*4) * 3;
            a0 += v.x*wp[0] + v.y*wp[3] + v.z*wp[6] + v.w*wp[9];
            a1 += v.x*wp[1] + v.y*wp[4] + v.z*wp[7] + v.w*wp[10];
            a2 += v.x*wp[2] + v.y*wp[5] + v.z*wp[8] + v.w*wp[11];
        }
        a0 = wred64(a0); a1 = wred64(a1); a2 = wred64(a2);
        s0 = a0 + bgW[s*3+0] + bgate[0];
        s1 = a1 + bgW[s*3+1] + bgate[1];
        s2 = a2 + bgW[s*3+2] + bgate[2];
    } else {
        s0 = bgate[0]; s1 = bgate[1]; s2 = bgate[2];
    }
    if (lane == 0) {
        const float mx = fmaxf(s0, fmaxf(s1, s2));
        const float e0 = expf(s0 - mx), e1 = expf(s1 - mx), e2 = expf(s2 - mx);
        const float inv = 1.f / (e0 + e1 + e2);
        float* o = out + O_GATE + (size_t)idx * NGATEc;
        o[0] = e0*inv; o[1] = e1*inv; o[2] = e2*inv;
    }
}

// ---------- Kernel E: softmax in place over L=512 ---------------------------
__global__ __launch_bounds__(256) void kE(
    const int* __restrict__ nsel, float* __restrict__ out)
{
    const int idx = blockIdx.x;             // b*SS + k
    const int b = idx / SS, k = idx % SS;
    const int tid = threadIdx.x;
    float* outs = out + O_SPROB + (size_t)idx * LL;
    float* oute = out + O_EPROB + (size_t)idx * LL;

    if (k >= nsel[b]) {                     // softmax(zeros) = 1/L exactly
        const float u = 1.0f / LL;
        outs[tid] = u; outs[tid + 256] = u;
        oute[tid] = u; oute[tid + 256] = u;
        return;
    }
    const int lane = tid & 63, wid = tid >> 6;
    __shared__ float rmax[2][4], rsum[2][4];

    const float s0 = outs[tid], s1 = outs[tid + 256];
    const float t0 = oute[tid], t1 = oute[tid + 256];

    float ms = fmaxf(s0, s1), me = fmaxf(t0, t1);
    #pragma unroll
    for (int o = 32; o; o >>= 1) { ms = fmaxf(ms, __shfl_xor(ms, o)); me = fmaxf(me, __shfl_xor(me, o)); }
    if (lane == 0) { rmax[0][wid] = ms; rmax[1][wid] = me; }
    __syncthreads();
    ms = fmaxf(fmaxf(rmax[0][0], rmax[0][1]), fmaxf(rmax[0][2], rmax[0][3]));
    me = fmaxf(fmaxf(rmax[1][0], rmax[1][1]), fmaxf(rmax[1][2], rmax[1][3]));

    const float e0 = expf(s0 - ms), e1 = expf(s1 - ms);
    const float f0 = expf(t0 - me), f1 = expf(t1 - me);
    float sa = e0 + e1, sb = f0 + f1;
    #pragma unroll
    for (int o = 32; o; o >>= 1) { sa += __shfl_xor(sa, o); sb += __shfl_xor(sb, o); }
    if (lane == 0) { rsum[0][wid] = sa; rsum[1][wid] = sb; }
    __syncthreads();
    const float inva = 1.f / (rsum[0][0] + rsum[0][1] + rsum[0][2] + rsum[0][3]);
    const float invb = 1.f / (rsum[1][0] + rsum[1][1] + rsum[1][2] + rsum[1][3]);

    outs[tid] = e0 * inva; outs[tid + 256] = e1 * inva;
    oute[tid] = f0 * invb; oute[tid + 256] = f1 * invb;
}

extern "C" void kernel_launch(void* const* d_in, const int* in_sizes, int n_in,
                              void* d_out, int out_size, void* d_ws, size_t ws_size,
                              hipStream_t stream)
{
    const float* H      = (const float*)d_in[0];
    const float* cls    = (const float*)d_in[1];
    const float* Wdom   = (const float*)d_in[2];
    const float* bdom   = (const float*)d_in[3];
    const float* Wslot  = (const float*)d_in[4];
    const float* bslot  = (const float*)d_in[5];
    const float* Wg     = (const float*)d_in[6];
    const float* bg     = (const float*)d_in[7];
    const float* Wgate  = (const float*)d_in[8];
    const float* bgate  = (const float*)d_in[9];
    const float* Wstart = (const float*)d_in[10];
    // d_in[11] b_start: constant per softmax row -> softmax-invariant, unused
    const float* Wend   = (const float*)d_in[12];
    // d_in[13] b_end: unused (same reason)
    const int* sp = (const int*)d_in[14];
    const int* sg = (const int*)d_in[15];

    float* out = (float*)d_out;
    float* wsf = (float*)d_ws;
    float* WgW = wsf + WS_WGW;
    float* bgW = wsf + WS_BGW;
    int* ipart  = (int*)(wsf + WS_INT);
    int* nptr   = ipart;
    int* nsel   = ipart + 64;
    int* ptrpos = ipart + 128;
    int* selpos = ptrpos + BB*SS;
    int* items  = selpos + BB*SS;
    int* NW     = items + MAXW;

    kA<<<BB, 256, 0, stream>>>(cls, Wdom, bdom, Wslot, bslot, sp, sg, out,
                               nptr, nsel, ptrpos, selpos);
    kA2<<<1, 64, 0, stream>>>(nsel, items, NW);
    kBD<<<KB_BLOCKS + KD_BLOCKS, 256, 0, stream>>>(H, Wstart, Wend, nsel, selpos, out,
                                                   Wg, bg, Wgate, WgW, bgW, items, NW);
    kC<<<(BB*SS) / 4, 256, 0, stream>>>(cls, WgW, bgW, bgate, nptr, ptrpos, out);
    kE<<<BB * SS, 256, 0, stream>>>(nsel, out);
}

// Round 9
// 71.032 us; speedup vs baseline: 1.2940x; 1.2940x over previous
//
#include <hip/hip_runtime.h>
#include <math.h>

// Problem constants (fixed by the reference setup)
constexpr int BB = 64, LL = 512, DD = 768, SS = 30;
constexpr int NDOMc = 5, NGATEc = 3, PRED = 2;

// Output layout (flat float32, reference return order)
constexpr size_t O_DOM   = 0;                               // (B,5)
constexpr size_t O_SPP   = O_DOM   + (size_t)BB*NDOMc;      // (B,30) sigmoid
constexpr size_t O_GATE  = O_SPP   + (size_t)BB*SS;         // (B,30,3) softmax
constexpr size_t O_SPTR  = O_GATE  + (size_t)BB*SS*NGATEc;  // (B,30) passthrough
constexpr size_t O_SGATE = O_SPTR  + (size_t)BB*SS;         // (B,30) passthrough
constexpr size_t O_SPROB = O_SGATE + (size_t)BB*SS;         // (B,30,512)
constexpr size_t O_EPROB = O_SPROB + (size_t)BB*SS*LL;      // (B,30,512)

// Workspace layout (floats): WgW[30*768*3], bgW[96], then ints
constexpr int WS_WGW = 0;
constexpr int WS_BGW = SS*DD*NGATEc;        // 69120
constexpr int WS_INT = WS_BGW + 96;         // 69216 (float offset where ints start)

constexpr int KB_ROWS = SS*DD + SS;         // 23070
constexpr int MAXW = BB * 4;                              // 256 items max (4-slot items)
constexpr int NCH = 16;                                   // 16 chunks x 32 rows
constexpr int KD_BLOCKS = MAXW * NCH;                     // 4096
constexpr int KB_BLOCKS = (KB_ROWS/2 + 3) / 4;            // 2884

__device__ __forceinline__ float wred64(float v) {
    #pragma unroll
    for (int o = 32; o; o >>= 1) v += __shfl_xor(v, o);
    return v;
}

// ---------- Kernel A: per-batch small dots, passthrough, scan/compaction ----
__global__ __launch_bounds__(256) void kA(
    const float* __restrict__ cls, const float* __restrict__ Wdom,
    const float* __restrict__ bdom, const float* __restrict__ Wslot,
    const float* __restrict__ bslot, const int* __restrict__ sp,
    const int* __restrict__ sg, float* __restrict__ out,
    int* __restrict__ nptr, int* __restrict__ nsel,
    int* __restrict__ ptrpos, int* __restrict__ selpos)
{
    const int b = blockIdx.x;
    const int tid = threadIdx.x, lane = tid & 63, wid = tid >> 6;
    const float* c = cls + (size_t)b * DD;

    for (int t = wid; t < NDOMc + SS; t += 4) {
        float acc = 0.f;
        if (t < NDOMc) {
            for (int d = lane; d < DD; d += 64) acc += c[d] * Wdom[d*NDOMc + t];
        } else {
            const int j = t - NDOMc;
            for (int d = lane; d < DD; d += 64) acc += c[d] * Wslot[d*SS + j];
        }
        acc = wred64(acc);
        if (lane == 0) {
            if (t < NDOMc) out[O_DOM + (size_t)b*NDOMc + t] = acc + bdom[t];
            else {
                const int j = t - NDOMc;
                const float x = acc + bslot[j];
                out[O_SPP + (size_t)b*SS + j] = 1.f / (1.f + expf(-x));
            }
        }
    }
    if (tid < SS) {
        out[O_SPTR  + (size_t)b*SS + tid] = (float)sp[b*SS + tid];
        out[O_SGATE + (size_t)b*SS + tid] = (float)sg[b*SS + tid];
    }
    // serial scan: ptr ranks and pmask compaction.
    // NOTE: gate_at_slot = slot_gate[b, clip(csum-1,0,M-1)] -> indexed by RANK.
    if (tid == 0) {
        int cp = 0, cs = 0;
        for (int i = 0; i < SS; ++i) {
            if (sp[b*SS + i] == 1) {
                const int rank = cp;            // csum-1 at this position
                ptrpos[b*SS + rank] = i;
                ++cp;
                if (sg[b*SS + rank] == PRED) { selpos[b*SS + cs] = i; ++cs; }
            }
        }
        nptr[b] = cp; nsel[b] = cs;
    }
}

// ---------- Kernel A2: compact (b, 4-slot group) work items, sorted by b ----
__global__ __launch_bounds__(64) void kA2(
    const int* __restrict__ nsel, int* __restrict__ items, int* __restrict__ NW)
{
    const int lane = threadIdx.x;               // 1 wave, lane == b
    const int ns = nsel[lane];
    const int cnt = (ns + 3) >> 2;              // ceil(ns/4) items
    int off = cnt;
    #pragma unroll
    for (int d = 1; d < 64; d <<= 1) {          // inclusive scan
        const int t = __shfl_up(off, d);
        if (lane >= d) off += t;
    }
    off -= cnt;                                 // exclusive prefix
    for (int i = 0; i < cnt; ++i) items[off + i] = lane * SS + 4*i;
    if (lane == 63) *NW = off + cnt;
}

// ---------- fused kBD: kB blocks first, then LDS-staged score blocks --------
__global__ __launch_bounds__(256) void kBD(
    const float* __restrict__ H, const float* __restrict__ Ws,
    const float* __restrict__ We, const int* __restrict__ nsel,
    const int* __restrict__ selpos, float* __restrict__ out,
    const float* __restrict__ Wg, const float* __restrict__ bg,
    const float* __restrict__ Wgate,
    float* __restrict__ WgW, float* __restrict__ bgW,
    const int* __restrict__ items, const int* __restrict__ NW)
{
    __shared__ float4 wlds[1536];               // [slot 4][se 2][d4 192] = 24 KB
    const int bid = blockIdx.x;
    const int tid = threadIdx.x;

    if (bid >= KB_BLOCKS) {
        // ---- scores: w-major / c-minor (16%8==0 -> chunk pins to XCD).
        // Dead blocks (w >= NW) are ONE contiguous tail. Weights staged in LDS
        // once per block -> inner loop is VALU-bound, no latency exposure.
        const int bidd = bid - KB_BLOCKS;
        const int w = bidd >> 4;                    // item index (major)
        const int c = bidd & 15;                    // chunk (minor), 32 rows
        if (w >= *NW) return;
        const int item = items[w];
        const int b = item / SS, k0 = item % SS;
        const int ns = nsel[b];

        // slot ids (replicate last valid slot for uniform compute)
        int sidx[4];
        #pragma unroll
        for (int t = 0; t < 4; ++t) {
            int kk = k0 + t; if (kk > ns - 1) kk = ns - 1;
            sidx[t] = selpos[b*SS + kk];
        }

        // stage 4 slots' W_start/W_end into LDS (6 float4 per thread)
        float4 stg[6];
        #pragma unroll
        for (int t = 0; t < 6; ++t) {
            const int j = tid + t*256;              // 0..1535
            const int slot = j / 384, rem = j % 384;
            const int se = rem / 192, d4 = rem % 192;
            const float* src = (se ? We : Ws) + (size_t)sidx[slot] * DD;
            stg[t] = ((const float4*)src)[d4];
        }

        const int grp = tid >> 4, m = tid & 15;     // 16 groups x 16 lanes
        const int l0 = c * 32 + grp;                // rows l0, l0+16
        const int l1 = l0 + 16;

        // H rows into registers (issued while staging loads are in flight)
        const float4* h40 = (const float4*)(H + ((size_t)b * LL + l0) * DD);
        const float4* h41 = (const float4*)(H + ((size_t)b * LL + l1) * DD);
        float4 hr0[12], hr1[12];
        #pragma unroll
        for (int j = 0; j < 12; ++j) hr0[j] = h40[j*16 + m];
        #pragma unroll
        for (int j = 0; j < 12; ++j) hr1[j] = h41[j*16 + m];

        #pragma unroll
        for (int t = 0; t < 6; ++t) wlds[tid + t*256] = stg[t];
        __syncthreads();

        #pragma unroll
        for (int t = 0; t < 4; ++t) {
            const float4* wls = wlds + t*384 + m;           // W_start slice
            const float4* wle = wlds + t*384 + 192 + m;     // W_end slice
            float a0=0.f, a1=0.f, e0=0.f, e1=0.f;
            #pragma unroll
            for (int j = 0; j < 12; ++j) {
                const float4 ww = wls[j*16];
                const float4 uu = wle[j*16];
                a0 += hr0[j].x*ww.x + hr0[j].y*ww.y + hr0[j].z*ww.z + hr0[j].w*ww.w;
                a1 += hr1[j].x*ww.x + hr1[j].y*ww.y + hr1[j].z*ww.z + hr1[j].w*ww.w;
                e0 += hr0[j].x*uu.x + hr0[j].y*uu.y + hr0[j].z*uu.z + hr0[j].w*uu.w;
                e1 += hr1[j].x*uu.x + hr1[j].y*uu.y + hr1[j].z*uu.z + hr1[j].w*uu.w;
            }
            #pragma unroll
            for (int o = 8; o; o >>= 1) {
                a0 += __shfl_xor(a0, o); a1 += __shfl_xor(a1, o);
                e0 += __shfl_xor(e0, o); e1 += __shfl_xor(e1, o);
            }
            const int ka = k0 + t;
            if (m == 0 && ka < ns) {
                out[O_SPROB + (size_t)(b*SS + ka) * LL + l0] = a0;
                out[O_SPROB + (size_t)(b*SS + ka) * LL + l1] = a1;
                out[O_EPROB + (size_t)(b*SS + ka) * LL + l0] = e0;
                out[O_EPROB + (size_t)(b*SS + ka) * LL + l1] = e1;
            }
        }
        return;
    }

    // ---- WgW precompute (bid < KB_BLOCKS): 2 rows per wave; pure HBM stream -
    const int lane = tid & 63, wid = tid >> 6;
    const int r0 = (bid * 4 + wid) * 2;
    if (r0 >= KB_ROWS) return;

    float wgt[3][4][3];
    #pragma unroll
    for (int j = 0; j < 3; ++j)
        #pragma unroll
        for (int cc = 0; cc < 4; ++cc) {
            const int e = j*256 + lane*4 + cc;
            #pragma unroll
            for (int g = 0; g < NGATEc; ++g) wgt[j][cc][g] = Wgate[e*NGATEc + g];
        }

    const float* src0 = (r0 < SS*DD) ? Wg + (size_t)r0*DD : bg + (size_t)(r0 - SS*DD)*DD;
    const int r1 = r0 + 1;
    const float* src1 = (r1 < SS*DD) ? Wg + (size_t)r1*DD : bg + (size_t)(r1 - SS*DD)*DD;
    float* dst0 = (r0 < SS*DD) ? WgW + (size_t)r0*3 : bgW + (r0 - SS*DD)*3;
    float* dst1 = (r1 < SS*DD) ? WgW + (size_t)r1*3 : bgW + (r1 - SS*DD)*3;

    const float4* s40 = (const float4*)src0;
    const float4* s41 = (const float4*)src1;
    float a0=0,a1=0,a2=0, c0=0,c1=0,c2=0;
    #pragma unroll
    for (int j = 0; j < 3; ++j) {
        const float4 v = s40[j*64 + lane];
        const float4 w2 = s41[j*64 + lane];
        a0 += v.x*wgt[j][0][0] + v.y*wgt[j][1][0] + v.z*wgt[j][2][0] + v.w*wgt[j][3][0];
        a1 += v.x*wgt[j][0][1] + v.y*wgt[j][1][1] + v.z*wgt[j][2][1] + v.w*wgt[j][3][1];
        a2 += v.x*wgt[j][0][2] + v.y*wgt[j][1][2] + v.z*wgt[j][2][2] + v.w*wgt[j][3][2];
        c0 += w2.x*wgt[j][0][0] + w2.y*wgt[j][1][0] + w2.z*wgt[j][2][0] + w2.w*wgt[j][3][0];
        c1 += w2.x*wgt[j][0][1] + w2.y*wgt[j][1][1] + w2.z*wgt[j][2][1] + w2.w*wgt[j][3][1];
        c2 += w2.x*wgt[j][0][2] + w2.y*wgt[j][1][2] + w2.z*wgt[j][2][2] + w2.w*wgt[j][3][2];
    }
    a0 = wred64(a0); a1 = wred64(a1); a2 = wred64(a2);
    c0 = wred64(c0); c1 = wred64(c1); c2 = wred64(c2);
    if (lane == 0) {
        dst0[0] = a0; dst0[1] = a1; dst0[2] = a2;
        dst1[0] = c0; dst1[1] = c1; dst1[2] = c2;
    }
}

// ---------- Kernel C: slot_gate_prob ----------------------------------------
__global__ __launch_bounds__(256) void kC(
    const float* __restrict__ cls, const float* __restrict__ WgW,
    const float* __restrict__ bgW, const float* __restrict__ bgate,
    const int* __restrict__ nptr, const int* __restrict__ ptrpos,
    float* __restrict__ out)
{
    const int lane = threadIdx.x & 63, wid = threadIdx.x >> 6;
    const int idx = blockIdx.x * 4 + wid;       // b*SS + m
    if (idx >= BB*SS) return;
    const int b = idx / SS, m = idx % SS;

    float s0, s1, s2;
    if (m < nptr[b]) {
        const int s = ptrpos[b*SS + m];
        const float4* c4 = (const float4*)(cls + (size_t)b * DD);
        float a0 = 0.f, a1 = 0.f, a2 = 0.f;
        #pragma unroll
        for (int j = 0; j < 3; ++j) {
            const float4 v = c4[j*64 + lane];
            const float* wp = WgW + ((size_t)s*DD + j*256 + lane*4) * 3;
            a0 += v.x*wp[0] + v.y*wp[3] + v.z*wp[6] + v.w*wp[9];
            a1 += v.x*wp[1] + v.y*wp[4] + v.z*wp[7] + v.w*wp[10];
            a2 += v.x*wp[2] + v.y*wp[5] + v.z*wp[8] + v.w*wp[11];
        }
        a0 = wred64(a0); a1 = wred64(a1); a2 = wred64(a2);
        s0 = a0 + bgW[s*3+0] + bgate[0];
        s1 = a1 + bgW[s*3+1] + bgate[1];
        s2 = a2 + bgW[s*3+2] + bgate[2];
    } else {
        s0 = bgate[0]; s1 = bgate[1]; s2 = bgate[2];
    }
    if (lane == 0) {
        const float mx = fmaxf(s0, fmaxf(s1, s2));
        const float e0 = expf(s0 - mx), e1 = expf(s1 - mx), e2 = expf(s2 - mx);
        const float inv = 1.f / (e0 + e1 + e2);
        float* o = out + O_GATE + (size_t)idx * NGATEc;
        o[0] = e0*inv; o[1] = e1*inv; o[2] = e2*inv;
    }
}

// ---------- Kernel E: softmax in place over L=512 ---------------------------
__global__ __launch_bounds__(256) void kE(
    const int* __restrict__ nsel, float* __restrict__ out)
{
    const int idx = blockIdx.x;             // b*SS + k
    const int b = idx / SS, k = idx % SS;
    const int tid = threadIdx.x;
    float* outs = out + O_SPROB + (size_t)idx * LL;
    float* oute = out + O_EPROB + (size_t)idx * LL;

    if (k >= nsel[b]) {                     // softmax(zeros) = 1/L exactly
        const float u = 1.0f / LL;
        outs[tid] = u; outs[tid + 256] = u;
        oute[tid] = u; oute[tid + 256] = u;
        return;
    }
    const int lane = tid & 63, wid = tid >> 6;
    __shared__ float rmax[2][4], rsum[2][4];

    const float s0 = outs[tid], s1 = outs[tid + 256];
    const float t0 = oute[tid], t1 = oute[tid + 256];

    float ms = fmaxf(s0, s1), me = fmaxf(t0, t1);
    #pragma unroll
    for (int o = 32; o; o >>= 1) { ms = fmaxf(ms, __shfl_xor(ms, o)); me = fmaxf(me, __shfl_xor(me, o)); }
    if (lane == 0) { rmax[0][wid] = ms; rmax[1][wid] = me; }
    __syncthreads();
    ms = fmaxf(fmaxf(rmax[0][0], rmax[0][1]), fmaxf(rmax[0][2], rmax[0][3]));
    me = fmaxf(fmaxf(rmax[1][0], rmax[1][1]), fmaxf(rmax[1][2], rmax[1][3]));

    const float e0 = expf(s0 - ms), e1 = expf(s1 - ms);
    const float f0 = expf(t0 - me), f1 = expf(t1 - me);
    float sa = e0 + e1, sb = f0 + f1;
    #pragma unroll
    for (int o = 32; o; o >>= 1) { sa += __shfl_xor(sa, o); sb += __shfl_xor(sb, o); }
    if (lane == 0) { rsum[0][wid] = sa; rsum[1][wid] = sb; }
    __syncthreads();
    const float inva = 1.f / (rsum[0][0] + rsum[0][1] + rsum[0][2] + rsum[0][3]);
    const float invb = 1.f / (rsum[1][0] + rsum[1][1] + rsum[1][2] + rsum[1][3]);

    outs[tid] = e0 * inva; outs[tid + 256] = e1 * inva;
    oute[tid] = f0 * invb; oute[tid + 256] = f1 * invb;
}

extern "C" void kernel_launch(void* const* d_in, const int* in_sizes, int n_in,
                              void* d_out, int out_size, void* d_ws, size_t ws_size,
                              hipStream_t stream)
{
    const float* H      = (const float*)d_in[0];
    const float* cls    = (const float*)d_in[1];
    const float* Wdom   = (const float*)d_in[2];
    const float* bdom   = (const float*)d_in[3];
    const float* Wslot  = (const float*)d_in[4];
    const float* bslot  = (const float*)d_in[5];
    const float* Wg     = (const float*)d_in[6];
    const float* bg     = (const float*)d_in[7];
    const float* Wgate  = (const float*)d_in[8];
    const float* bgate  = (const float*)d_in[9];
    const float* Wstart = (const float*)d_in[10];
    // d_in[11] b_start: constant per softmax row -> softmax-invariant, unused
    const float* Wend   = (const float*)d_in[12];
    // d_in[13] b_end: unused (same reason)
    const int* sp = (const int*)d_in[14];
    const int* sg = (const int*)d_in[15];

    float* out = (float*)d_out;
    float* wsf = (float*)d_ws;
    float* WgW = wsf + WS_WGW;
    float* bgW = wsf + WS_BGW;
    int* ipart  = (int*)(wsf + WS_INT);
    int* nptr   = ipart;
    int* nsel   = ipart + 64;
    int* ptrpos = ipart + 128;
    int* selpos = ptrpos + BB*SS;
    int* items  = selpos + BB*SS;
    int* NW     = items + MAXW;

    kA<<<BB, 256, 0, stream>>>(cls, Wdom, bdom, Wslot, bslot, sp, sg, out,
                               nptr, nsel, ptrpos, selpos);
    kA2<<<1, 64, 0, stream>>>(nsel, items, NW);
    kBD<<<KB_BLOCKS + KD_BLOCKS, 256, 0, stream>>>(H, Wstart, Wend, nsel, selpos, out,
                                                   Wg, bg, Wgate, WgW, bgW, items, NW);
    kC<<<(BB*SS) / 4, 256, 0, stream>>>(cls, WgW, bgW, bgate, nptr, ptrpos, out);
    kE<<<BB * SS, 256, 0, stream>>>(nsel, out);
}